// Round 7
// baseline (378.782 us; speedup 1.0000x reference)
//
#include <hip/hip_runtime.h>
#include <cstddef>

#define BB 32
#define TT 64
#define NN_ 2048
#define SS 2048
#define DD 256
#define GG 1024
#define FLD 264 // padded feat leading dim (16B-aligned rows, >=258)

typedef __attribute__((ext_vector_type(8))) short short8;
typedef __attribute__((ext_vector_type(4))) float f32x4;
typedef _Float16 h2_t __attribute__((ext_vector_type(2)));

static __device__ inline unsigned short f2bf(float f) {
    union { float f; unsigned int u; } v; v.f = f;
    unsigned int u = v.u;
    unsigned int r = u + 0x7FFF + ((u >> 16) & 1);   // RNE
    return (unsigned short)(r >> 16);
}

static __device__ inline short8 pack8(float4 a, float4 b) {
    short8 s;
    s[0] = (short)f2bf(a.x); s[1] = (short)f2bf(a.y);
    s[2] = (short)f2bf(a.z); s[3] = (short)f2bf(a.w);
    s[4] = (short)f2bf(b.x); s[5] = (short)f2bf(b.y);
    s[6] = (short)f2bf(b.z); s[7] = (short)f2bf(b.w);
    return s;
}

static __device__ inline h2_t as_h2(unsigned int u) {
    union { unsigned int u; h2_t h; } v; v.u = u; return v.h;
}
static __device__ inline unsigned int h2_pack(float a, float b) {
    union { unsigned int u; h2_t h; } v;
    v.h[0] = (_Float16)a; v.h[1] = (_Float16)b; return v.u;
}

#if __has_builtin(__builtin_amdgcn_fdot2)
static __device__ inline float fdot2(h2_t a, h2_t b, float c) {
    return __builtin_amdgcn_fdot2(a, b, c, false);
}
#else
static __device__ inline float fdot2(h2_t a, h2_t b, float c) {
    return c + (float)a[0] * (float)b[0] + (float)a[1] * (float)b[1];
}
#endif

static __device__ inline float sigm(float x) { return 1.0f / (1.0f + __expf(-x)); }
static __device__ inline float tanh_f(float x) {
    float xc = fminf(fmaxf(x, -20.0f), 20.0f);
    float e = __expf(-2.0f * xc);
    return (1.0f - e) / (1.0f + e);
}

// ---------------- prep kernels ----------------

__global__ __launch_bounds__(256) void k_gather(const float* __restrict__ emb,
                                                const int* __restrict__ gt,
                                                const float* __restrict__ go,
                                                float* __restrict__ x) {
    int idx = blockIdx.x * 256 + threadIdx.x;     // over B*T*D = 524288
    int d = idx & (DD - 1);
    int t = (idx >> 8) & (TT - 1);
    int b = idx >> 14;
    float v;
    if (t == 0) v = go[d];
    else        v = emb[((size_t)b * NN_ + gt[b * TT + t - 1]) * DD + d];
    x[idx] = v;
}

__global__ __launch_bounds__(256) void k_first_init(int* __restrict__ firstpos) {
    int idx = blockIdx.x * 256 + threadIdx.x;     // B*N
    firstpos[idx] = TT;                            // "never picked"
}

__global__ __launch_bounds__(256) void k_first_min(const int* __restrict__ gt,
                                                   int* __restrict__ firstpos) {
    int idx = blockIdx.x * 256 + threadIdx.x;     // B*T = 2048
    int b = idx / TT;
    int t = idx % TT;
    atomicMin(&firstpos[(size_t)b * NN_ + gt[idx]], t);
}

// WhhT16[k2*1024 + g] = f16pair(Whh[g][2*k2], Whh[g][2*k2+1])
__global__ __launch_bounds__(256) void k_whhT16(const float* __restrict__ Whh,
                                                unsigned int* __restrict__ WhhT16) {
    int idx = blockIdx.x * 256 + threadIdx.x;     // over 1024*128
    int k2 = idx & 127;
    int g = idx >> 7;
    float2 w = *(const float2*)(Whh + (size_t)g * DD + 2 * k2);
    WhhT16[(size_t)k2 * GG + g] = h2_pack(w.x, w.y);
}

// cat = [hs | attn] : [B*T, 512]
__global__ __launch_bounds__(256) void k_cat(const float* __restrict__ hs,
                                             const float* __restrict__ attn,
                                             float* __restrict__ cat) {
    int idx = blockIdx.x * 256 + threadIdx.x;     // over B*T*512
    int d = idx & 511;
    int bt = idx >> 9;
    cat[idx] = (d < DD) ? hs[(size_t)bt * DD + d]
                        : attn[(size_t)bt * DD + (d - DD)];
}

// ---------------- bf16 MFMA NT GEMM ----------------
__global__ __launch_bounds__(256) void gemm_bf16_nt(
        const float* __restrict__ A, const float* __restrict__ Bm,
        float* __restrict__ C, int K, int lda, int ldb, int ldc,
        long sA, long sB, long sC, int Nlim,
        const float* __restrict__ bias1, const float* __restrict__ bias2,
        const int* __restrict__ firstpos, const float* __restrict__ emb_mask,
        int fscol) {
    int bz = blockIdx.z;
    A += (size_t)bz * sA; Bm += (size_t)bz * sB; C += (size_t)bz * sC;
    int tm = blockIdx.y * 64, tn = blockIdx.x * 64;
    __shared__ short Ab[64][72];
    __shared__ short Bb[64][72];
    __shared__ float sfs[64];
    int tid = threadIdx.x, lane = tid & 63, wid = tid >> 6;
    int wm = wid & 1, wn = wid >> 1;   // wave -> 32x32 quadrant

    if (fscol >= 0 && tid < 64) sfs[tid] = A[(size_t)(tm + tid) * lda + fscol];

    f32x4 zero = {0.f, 0.f, 0.f, 0.f};
    f32x4 acc[2][2] = {{zero, zero}, {zero, zero}};

    int row = tid >> 2, kk = (tid & 3) * 16;
    int brow = tn + row; if (brow >= Nlim) brow = Nlim - 1;
    const float* ap = &A[(size_t)(tm + row) * lda + kk];
    const float* bp = &Bm[(size_t)brow * ldb + kk];

    for (int k0 = 0; k0 < K; k0 += 64) {
        float4 a0 = *(const float4*)(ap + k0);
        float4 a1 = *(const float4*)(ap + k0 + 4);
        float4 a2 = *(const float4*)(ap + k0 + 8);
        float4 a3 = *(const float4*)(ap + k0 + 12);
        float4 b0 = *(const float4*)(bp + k0);
        float4 b1 = *(const float4*)(bp + k0 + 4);
        float4 b2 = *(const float4*)(bp + k0 + 8);
        float4 b3 = *(const float4*)(bp + k0 + 12);
        *(short8*)&Ab[row][kk]     = pack8(a0, a1);
        *(short8*)&Ab[row][kk + 8] = pack8(a2, a3);
        *(short8*)&Bb[row][kk]     = pack8(b0, b1);
        *(short8*)&Bb[row][kk + 8] = pack8(b2, b3);
        __syncthreads();
#pragma unroll
        for (int kt = 0; kt < 2; ++kt) {
            int k8 = kt * 32 + (lane >> 4) * 8;
            short8 fa0 = *(const short8*)&Ab[wm * 32 + (lane & 15)][k8];
            short8 fa1 = *(const short8*)&Ab[wm * 32 + 16 + (lane & 15)][k8];
            short8 fb0 = *(const short8*)&Bb[wn * 32 + (lane & 15)][k8];
            short8 fb1 = *(const short8*)&Bb[wn * 32 + 16 + (lane & 15)][k8];
            acc[0][0] = __builtin_amdgcn_mfma_f32_16x16x32_bf16(fa0, fb0, acc[0][0], 0, 0, 0);
            acc[0][1] = __builtin_amdgcn_mfma_f32_16x16x32_bf16(fa0, fb1, acc[0][1], 0, 0, 0);
            acc[1][0] = __builtin_amdgcn_mfma_f32_16x16x32_bf16(fa1, fb0, acc[1][0], 0, 0, 0);
            acc[1][1] = __builtin_amdgcn_mfma_f32_16x16x32_bf16(fa1, fb1, acc[1][1], 0, 0, 0);
        }
        __syncthreads();
    }

#pragma unroll
    for (int i = 0; i < 2; ++i) {
#pragma unroll
        for (int j = 0; j < 2; ++j) {
#pragma unroll
            for (int r = 0; r < 4; ++r) {
                int lrow = wm * 32 + i * 16 + (lane >> 4) * 4 + r;
                int gcol = tn + wn * 32 + j * 16 + (lane & 15);
                if (gcol < Nlim) {
                    float v = acc[i][j][r];
                    if (bias1) v += bias1[gcol];
                    if (bias2) v += bias2[gcol];
                    if (firstpos) {
                        int grow = tm + lrow;
                        if (firstpos[(size_t)bz * NN_ + gcol] < grow) v += sfs[lrow];
                        v -= (1.0f - emb_mask[(size_t)bz * NN_ + gcol]) * 1e20f;
                    }
                    C[(size_t)(tm + lrow) * ldc + gcol] = v;
                }
            }
        }
    }
}

// ---------------- attn = w @ enc (NN) via MFMA, B transposed at frag-read ----
__global__ __launch_bounds__(256) void gemm_attn(const float* __restrict__ W,
                                                 const float* __restrict__ enc,
                                                 float* __restrict__ attn) {
    int b = blockIdx.z;
    int tn = blockIdx.x * 64;   // d-tile
    const float* Wb = W + (size_t)b * TT * SS;
    const float* Eb = enc + (size_t)b * SS * DD;
    float* Cb = attn + (size_t)b * TT * DD;
    __shared__ short As[64][72];
    __shared__ float Bs[64][66];
    int tid = threadIdx.x, lane = tid & 63, wid = tid >> 6;
    int wm = wid & 1, wn = wid >> 1;
    f32x4 zero = {0.f, 0.f, 0.f, 0.f};
    f32x4 acc[2][2] = {{zero, zero}, {zero, zero}};
    int row = tid >> 2, kk = (tid & 3) * 16;
    const float* ap = Wb + (size_t)row * SS + kk;        // A row = t, k = s
    const float* bp = Eb + (size_t)row * DD + tn + kk;   // B row = s, col = d

    for (int k0 = 0; k0 < SS; k0 += 64) {
        float4 a0 = *(const float4*)(ap + k0);
        float4 a1 = *(const float4*)(ap + k0 + 4);
        float4 a2 = *(const float4*)(ap + k0 + 8);
        float4 a3 = *(const float4*)(ap + k0 + 12);
        *(short8*)&As[row][kk]     = pack8(a0, a1);
        *(short8*)&As[row][kk + 8] = pack8(a2, a3);
        const float* bq = bp + (size_t)k0 * DD;
#pragma unroll
        for (int i = 0; i < 8; ++i)
            *(float2*)&Bs[row][kk + 2 * i] = *(const float2*)(bq + 2 * i);
        __syncthreads();
#pragma unroll
        for (int kt = 0; kt < 2; ++kt) {
            int k8 = kt * 32 + (lane >> 4) * 8;
            short8 fa0 = *(const short8*)&As[wm * 32 + (lane & 15)][k8];
            short8 fa1 = *(const short8*)&As[wm * 32 + 16 + (lane & 15)][k8];
            short8 fb0, fb1;
#pragma unroll
            for (int e = 0; e < 8; ++e) {
                fb0[e] = (short)f2bf(Bs[k8 + e][wn * 32 + (lane & 15)]);
                fb1[e] = (short)f2bf(Bs[k8 + e][wn * 32 + 16 + (lane & 15)]);
            }
            acc[0][0] = __builtin_amdgcn_mfma_f32_16x16x32_bf16(fa0, fb0, acc[0][0], 0, 0, 0);
            acc[0][1] = __builtin_amdgcn_mfma_f32_16x16x32_bf16(fa0, fb1, acc[0][1], 0, 0, 0);
            acc[1][0] = __builtin_amdgcn_mfma_f32_16x16x32_bf16(fa1, fb0, acc[1][0], 0, 0, 0);
            acc[1][1] = __builtin_amdgcn_mfma_f32_16x16x32_bf16(fa1, fb1, acc[1][1], 0, 0, 0);
        }
        __syncthreads();
    }

#pragma unroll
    for (int i = 0; i < 2; ++i)
#pragma unroll
        for (int j = 0; j < 2; ++j)
#pragma unroll
            for (int r = 0; r < 4; ++r) {
                int lrow = wm * 32 + i * 16 + (lane >> 4) * 4 + r;
                int gcol = tn + wn * 32 + j * 16 + (lane & 15);
                Cb[(size_t)lrow * DD + gcol] = acc[i][j][r];
            }
}

// ---------------- LSTM v4: batch-local, zero inter-block sync --------------
// Block b owns batch b. Thread g owns gate-row g (gate=g>>8, unit=g&255).
// Whh row g register-resident as 128 packed f16 pairs (coalesced load from
// the pre-transposed WhhT16). h lives in 512B of LDS as f16 pairs; per step:
// 128 fdot2 -> preact LDS roundtrip -> in-lane activation on threads 0..255
// -> repack h. Two __syncthreads per step; no global traffic except xW in
// and hs out.
__global__ __launch_bounds__(1024) void k_lstm_local(const float* __restrict__ xW,
                                                     const unsigned int* __restrict__ WhhT16,
                                                     float* __restrict__ hs) {
    int b = blockIdx.x;
    int g = threadIdx.x;           // 0..1023

    unsigned int wreg[128];
#pragma unroll
    for (int i = 0; i < 128; ++i)
        wreg[i] = WhhT16[(size_t)i * GG + g];   // coalesced: lanes consecutive g

    __shared__ uint4 h2q[32];      // 128 f16-pairs = 256 h values
    __shared__ float pre[1024];
    if (g < 32) h2q[g] = make_uint4(0, 0, 0, 0);
    __syncthreads();

    float cstate = 0.0f;
    const float* xwb = xW + (size_t)b * TT * GG + g;

    for (int t = 0; t < TT; ++t) {
        float xw = xwb[t * GG];    // issued early; latency hides under fdot2
        float a0 = 0.f, a1 = 0.f, a2 = 0.f, a3 = 0.f;
#pragma unroll
        for (int i = 0; i < 32; ++i) {
            uint4 q = h2q[i];
            a0 = fdot2(as_h2(q.x), as_h2(wreg[4 * i + 0]), a0);
            a1 = fdot2(as_h2(q.y), as_h2(wreg[4 * i + 1]), a1);
            a2 = fdot2(as_h2(q.z), as_h2(wreg[4 * i + 2]), a2);
            a3 = fdot2(as_h2(q.w), as_h2(wreg[4 * i + 3]), a3);
        }
        pre[g] = ((a0 + a1) + (a2 + a3)) + xw;
        __syncthreads();

        if (g < 256) {
            float pi = pre[g], pf = pre[g + 256], pg = pre[g + 512], po = pre[g + 768];
            float ig = sigm(pi);
            float fg = sigm(pf);
            float gg = tanh_f(pg);
            float og = sigm(po);
            cstate = fg * cstate + ig * gg;
            float hn = og * tanh_f(cstate);
            hs[((size_t)b * TT + t) * DD + g] = hn;
            float hnb = __shfl_down(hn, 1);
            if (!(g & 1))
                ((unsigned int*)h2q)[g >> 1] = h2_pack(hn, hnb);
        }
        __syncthreads();
    }
}

// ---------------- softmax over S (in place, masked) ----------------
__global__ __launch_bounds__(256) void k_softmax(float* __restrict__ raw,
                                                 const float* __restrict__ enc_mask) {
    int bt = blockIdx.x;
    int b = bt / TT;
    float* r = raw + (size_t)bt * SS;
    __shared__ float row[SS];
    __shared__ float red[16];
    int tid = threadIdx.x;
    float mx = -1e30f;
    for (int s = tid; s < SS; s += 256) {
        float v = r[s] - (1.0f - enc_mask[(size_t)b * SS + s]) * 1e20f;
        row[s] = v;
        mx = fmaxf(mx, v);
    }
#pragma unroll
    for (int o = 32; o > 0; o >>= 1) mx = fmaxf(mx, __shfl_down(mx, o));
    if ((tid & 63) == 0) red[tid >> 6] = mx;
    __syncthreads();
    if (tid == 0) {
        float m2 = red[0];
        for (int i = 1; i < 4; ++i) m2 = fmaxf(m2, red[i]);
        red[0] = m2;
    }
    __syncthreads();
    mx = red[0];
    float sum = 0.0f;
    for (int s = tid; s < SS; s += 256) {
        float e = expf(row[s] - mx);
        row[s] = e;
        sum += e;
    }
#pragma unroll
    for (int o = 32; o > 0; o >>= 1) sum += __shfl_down(sum, o);
    if ((tid & 63) == 0) red[8 + (tid >> 6)] = sum;
    __syncthreads();
    if (tid == 0) {
        float s = red[8];
        for (int i = 1; i < 4; ++i) s += red[8 + i];
        red[8] = s;
    }
    __syncthreads();
    float inv = 1.0f / red[8];
    for (int s = tid; s < SS; s += 256) r[s] = row[s] * inv;
}

// ---------------- launch ----------------
extern "C" void kernel_launch(void* const* d_in, const int* in_sizes, int n_in,
                              void* d_out, int out_size, void* d_ws, size_t ws_size,
                              hipStream_t stream) {
    const float* emb      = (const float*)d_in[0];
    const float* emb_mask = (const float*)d_in[1];
    const float* enc      = (const float*)d_in[2];
    const float* enc_mask = (const float*)d_in[3];
    const int*   gt       = (const int*)d_in[4];
    const float* go       = (const float*)d_in[5];
    const float* Wih      = (const float*)d_in[6];
    const float* Whh      = (const float*)d_in[7];
    const float* bih      = (const float*)d_in[8];
    const float* bhh      = (const float*)d_in[9];
    const float* Wdt      = (const float*)d_in[10];
    const float* bdt      = (const float*)d_in[11];
    const float* Wf       = (const float*)d_in[12];
    const float* bf       = (const float*)d_in[13];
    float* out = (float*)d_out;

    float* ws    = (float*)d_ws;
    float* x     = ws;                                   // [B*T*D]
    float* xW    = x     + (size_t)BB * TT * DD;         // [B*T*G]
    float* hs    = xW    + (size_t)BB * TT * GG;         // [B*T*D]
    float* dec   = hs    + (size_t)BB * TT * DD;         // [B*T*D]
    float* w     = dec   + (size_t)BB * TT * DD;         // [B*T*S]
    float* attn  = w     + (size_t)BB * TT * SS;         // [B*T*D]
    float* feat  = attn  + (size_t)BB * TT * DD;         // [B*T*FLD]
    float* cat   = feat  + (size_t)BB * TT * FLD;        // [B*T*512]
    float* cat_end = cat + (size_t)BB * TT * 512;
    int* firstpos = (int*)cat_end;                       // [B*N]
    unsigned int* WhhT16 = (unsigned int*)(firstpos + (size_t)BB * NN_); // [128*1024] u32 (512KB)

    k_gather<<<BB * TT * DD / 256, 256, 0, stream>>>(emb, gt, go, x);
    k_first_init<<<BB * NN_ / 256, 256, 0, stream>>>(firstpos);
    k_first_min<<<BB * TT / 256, 256, 0, stream>>>(gt, firstpos);
    k_whhT16<<<GG * 128 / 256, 256, 0, stream>>>(Whh, WhhT16);

    // xW = x @ Wih^T + bih + bhh : [2048,1024]
    gemm_bf16_nt<<<dim3(GG / 64, BB * TT / 64, 1), 256, 0, stream>>>(
        x, Wih, xW, DD, DD, DD, GG, 0, 0, 0, GG,
        bih, bhh, nullptr, nullptr, -1);

    k_lstm_local<<<BB, 1024, 0, stream>>>(xW, WhhT16, hs);

    // dec = hs @ Wdt^T + bdt : [2048,256]
    gemm_bf16_nt<<<dim3(DD / 64, BB * TT / 64, 1), 256, 0, stream>>>(
        hs, Wdt, dec, DD, DD, DD, DD, 0, 0, 0, DD,
        bdt, nullptr, nullptr, nullptr, -1);

    // raw[b] = dec[b] @ enc[b]^T : [64,2048], batch 32
    gemm_bf16_nt<<<dim3(SS / 64, 1, BB), 256, 0, stream>>>(
        dec, enc, w, DD, DD, DD, SS,
        (long)TT * DD, (long)SS * DD, (long)TT * SS, SS,
        nullptr, nullptr, nullptr, nullptr, -1);

    k_softmax<<<BB * TT, 256, 0, stream>>>(w, enc_mask);

    // attn[b] = w[b] @ enc[b] : [64,256], batch 32  (MFMA, inline transpose)
    gemm_attn<<<dim3(DD / 64, 1, BB), 256, 0, stream>>>(w, enc, attn);

    // cat = [hs | attn]
    k_cat<<<BB * TT * 512 / 256, 256, 0, stream>>>(hs, attn, cat);

    // feat = cat @ Wf^T + bf : [2048, 257] (ld FLD)
    gemm_bf16_nt<<<dim3(5, BB * TT / 64, 1), 256, 0, stream>>>(
        cat, Wf, feat, 2 * DD, 2 * DD, 2 * DD, FLD, 0, 0, 0, DD + 1,
        bf, nullptr, nullptr, nullptr, -1);

    // score[b] = feat[b,:, :256] @ emb[b]^T (+ picked, mask)
    gemm_bf16_nt<<<dim3(NN_ / 64, 1, BB), 256, 0, stream>>>(
        feat, emb, out, DD, FLD, DD, NN_,
        (long)TT * FLD, (long)NN_ * DD, (long)TT * NN_, NN_,
        nullptr, nullptr, firstpos, emb_mask, 256);
}